// Round 20
// baseline (56.140 us; speedup 1.0000x reference)
//
#include <hip/hip_runtime.h>
#include <math.h>

#define NPTS 8192
#define DIM 512
#define KNN 5

typedef unsigned short u16;
typedef unsigned char u8;
typedef unsigned int u32;
typedef __attribute__((ext_vector_type(8))) int i32x8;
typedef __attribute__((ext_vector_type(4))) float f32x4;
typedef __attribute__((ext_vector_type(16))) float f32x16;

// Branch-free sorted insert of v into ascending 5-list.
// Closed form: t_i' = med3(t_{i-1}, t_i, v) (old values), t0' = min(t0, v).
#define INSERT5(t0, t1, t2, t3, t4, v)                \
  do {                                                \
    float _v = (v);                                   \
    float _n4 = __builtin_amdgcn_fmed3f(t3, t4, _v);  \
    float _n3 = __builtin_amdgcn_fmed3f(t2, t3, _v);  \
    float _n2 = __builtin_amdgcn_fmed3f(t1, t2, _v);  \
    float _n1 = __builtin_amdgcn_fmed3f(t0, t1, _v);  \
    t0 = fminf(t0, _v);                               \
    t1 = _n1; t2 = _n2; t3 = _n3; t4 = _n4;           \
  } while (0)

// ---------------------------------------------------------------------------
// Kernel 0: fused fp8-e4m3 convert (to 32x32x64 f8f6f4 MFMA band pack)+sumsq.
// Also zeroes the global accumulator/ticket (ws is NOT re-poisoned between
// graph replays -- every call must reset its own state).
// MX fp8 A/B fragment (8 VGPR, 32 B): row = lane&31, k = (lane>>5)*32 + byte.
// Band layout (64 rows, byte address):
//   band G = row>>6 (32768 B); iter I = k>>6 (4096 B); mf2 = (row>>5)&1 (2048);
//   frag_lane = ((k>>5)&1)*32 + (row&31) (32 B); byte = k&31.
__global__ __launch_bounds__(256) void k_prep(const float* __restrict__ X,
                                              u8* __restrict__ Xp8,
                                              float* __restrict__ sq,
                                              double* __restrict__ acc,
                                              u32* __restrict__ cnt) {
  int gt = blockIdx.x * 256 + threadIdx.x;
  if (gt == 0) {           // reset global reduction state for this call
    acc[0] = 0.0;
    acc[1] = 0.0;
    cnt[0] = 0u;
  }
  int row = gt >> 6;
  int lane = gt & 63;   // holds k = lane*8 .. lane*8+7 (one 8-byte octet)
  const float* r = X + (size_t)row * DIM + lane * 8;
  float4 a = *(const float4*)r;
  float4 b = *(const float4*)(r + 4);
  float s = a.x * a.x + a.y * a.y + a.z * a.z + a.w * a.w
          + b.x * b.x + b.y * b.y + b.z * b.z + b.w * b.w;
  u32 w0 = __builtin_amdgcn_cvt_pk_fp8_f32(a.x, a.y, 0u, false);
  w0 = __builtin_amdgcn_cvt_pk_fp8_f32(a.z, a.w, w0, true);
  u32 w1 = __builtin_amdgcn_cvt_pk_fp8_f32(b.x, b.y, 0u, false);
  w1 = __builtin_amdgcn_cvt_pk_fp8_f32(b.z, b.w, w1, true);
  // k0 = lane*8: iter = lane>>3; kb = (lane&7)*8; kb>>5 = (lane>>2)&1;
  // byte = kb&31 = (lane&3)*8
  u32 dst = (u32)((row >> 6) * 32768 + (lane >> 3) * 4096 +
                  ((row >> 5) & 1) * 2048 +
                  (((lane >> 2) & 1) * 32 + (row & 31)) * 32 + (lane & 3) * 8);
  *(uint2*)(Xp8 + dst) = make_uint2(w0, w1);
#pragma unroll
  for (int o = 32; o > 0; o >>= 1) s += __shfl_down(s, o);
  if (lane == 0) sq[row] = s;
}

// ---------------------------------------------------------------------------
// Kernel 1: symmetric MX-fp8 32x32x64 MFMA distance tiles, triangular grid.
// (Unchanged from R19 -- measured plateau config.) Single-buffered frags,
// rolled loop, launch_bounds(256,4); 8x8 super-tile keeps fp8 panels in L2.
// C/D: col=lane&31, row=(reg&3)+8*(reg>>2)+4*(lane>>5). part holds d^2.
__global__ __launch_bounds__(256, 4) void k_knn_sym(
    const u8* __restrict__ Xp8, const float* __restrict__ sq,
    float* __restrict__ part) {
  __shared__ __align__(16) char smem[34816];
  float* mbuf = (float*)smem;             // col-epi merge: [wm*2+wn][nf2][32][5]
  float* lsT = (float*)smem;              // row-epi transpose: [128 cols][68]

  const int tid = threadIdx.x;
  const int lane = tid & 63;
  const int wid = tid >> 6;
  const int wm = wid >> 1;
  const int wn = wid & 1;
  const int lh = lane >> 5;               // row-half selector for C/D

  // XCD-aware bijective remap (2080 = 8 * 260) -> 8x8 super-tiles per XCD
  int t = (blockIdx.x & 7) * 260 + (blockIdx.x >> 3);
  int bm, bn;
  if (t < 1792) {
    int st = t >> 6, u = t & 63;
    int SM = (int)((sqrtf(8.f * st + 1.f) + 1.f) * 0.5f);
    while (SM * (SM - 1) / 2 > st) --SM;
    while ((SM + 1) * SM / 2 <= st) ++SM;
    int SN = st - SM * (SM - 1) / 2;
    bm = SM * 8 + (u >> 3);
    bn = SN * 8 + (u & 7);
  } else {
    int d = t - 1792;
    int SM = d / 36, u = d % 36;
    int im = (int)((sqrtf(8.f * u + 1.f) - 1.f) * 0.5f);
    while ((im + 1) * (im + 2) / 2 <= u) ++im;
    while (im * (im + 1) / 2 > u) --im;
    int in = u - im * (im + 1) / 2;
    bm = SM * 8 + im;
    bn = SM * 8 + in;
  }
  const int n0 = bm * 128;
  const int q0 = bn * 128;

  // Band pointers: band (64 rows) = 32768 B; advance 4096 B per K-64 iter.
  const u8* pa = Xp8 + (size_t)(bm * 2 + wm) * 32768 + lane * 32;
  const u8* pb = Xp8 + (size_t)(bn * 2 + wn) * 32768 + lane * 32;

  // 32B fragment load = two dwordx4
#define LD32(dst, p)                                           \
  do {                                                         \
    uint4 _lo = *(const uint4*)(p);                            \
    uint4 _hi = *(const uint4*)((p) + 16);                     \
    dst[0] = (int)_lo.x; dst[1] = (int)_lo.y;                  \
    dst[2] = (int)_lo.z; dst[3] = (int)_lo.w;                  \
    dst[4] = (int)_hi.x; dst[5] = (int)_hi.y;                  \
    dst[6] = (int)_hi.z; dst[7] = (int)_hi.w;                  \
  } while (0)

  f32x16 acc[2][2];
#pragma unroll
  for (int mf2 = 0; mf2 < 2; ++mf2)
#pragma unroll
    for (int nf2 = 0; nf2 < 2; ++nf2)
#pragma unroll
      for (int r = 0; r < 16; ++r) acc[mf2][nf2][r] = 0.f;

  i32x8 afr[2], bfr[2];                   // single-buffered [mf2/nf2]
#pragma unroll 1
  for (int step = 0; step < DIM / 64; ++step) {        // 8 iters of K=64
    LD32(afr[0], pa);
    LD32(afr[1], pa + 2048);
    LD32(bfr[0], pb);
    LD32(bfr[1], pb + 2048);
    pa += 4096;
    pb += 4096;
    __builtin_amdgcn_s_setprio(1);
#pragma unroll
    for (int mf2 = 0; mf2 < 2; ++mf2)
#pragma unroll
      for (int nf2 = 0; nf2 < 2; ++nf2)
        acc[mf2][nf2] = __builtin_amdgcn_mfma_scale_f32_32x32x64_f8f6f4(
            afr[mf2], bfr[nf2], acc[mf2][nf2],
            0, 0,            // cbsz/blgp: fp8 e4m3 / fp8 e4m3
            0, 127,          // scale A: opsel 0, e8m0 127 = 1.0
            0, 127);         // scale B: opsel 0, e8m0 127 = 1.0
    __builtin_amdgcn_s_setprio(0);
  }
#undef LD32

  // ---- column epilogue: per query-col top-5 of (sq_row - 2*dot) ----
  int qg[2];
  float sqc[2];
#pragma unroll
  for (int nf2 = 0; nf2 < 2; ++nf2) {
    qg[nf2] = q0 + wn * 64 + nf2 * 32 + (lane & 31);
    sqc[nf2] = sq[qg[nf2]];
  }

  float tl[2][5];
#pragma unroll
  for (int nf2 = 0; nf2 < 2; ++nf2)
#pragma unroll
    for (int j = 0; j < 5; ++j) tl[nf2][j] = 1e30f;

  // diagonal mask needed only on the 64 diagonal tiles (uniform branch)
#define COLSCAN(DIAG)                                                         \
  do {                                                                        \
    _Pragma("unroll")                                                         \
    for (int mf2 = 0; mf2 < 2; ++mf2) {                                       \
      _Pragma("unroll")                                                       \
      for (int q2 = 0; q2 < 4; ++q2) {                                        \
        int ngb = n0 + wm * 64 + mf2 * 32 + q2 * 8 + 4 * lh;                  \
        float4 snv = *(const float4*)&sq[ngb];                                \
        _Pragma("unroll")                                                     \
        for (int j = 0; j < 4; ++j) {                                         \
          float sn = (j == 0) ? snv.x : (j == 1) ? snv.y                      \
                   : (j == 2) ? snv.z : snv.w;                                \
          _Pragma("unroll")                                                   \
          for (int nf2 = 0; nf2 < 2; ++nf2) {                                 \
            float c = fmaf(-2.f, acc[mf2][nf2][q2 * 4 + j], sn);              \
            if (DIAG) c = ((ngb + j) == qg[nf2]) ? -1e30f : c;                \
            INSERT5(tl[nf2][0], tl[nf2][1], tl[nf2][2], tl[nf2][3],           \
                    tl[nf2][4], c);                                           \
          }                                                                   \
        }                                                                     \
      }                                                                       \
    }                                                                         \
  } while (0)

  if (bm == bn) COLSCAN(true); else COLSCAN(false);
#undef COLSCAN

  // merge with partner lane^32 (holds the complementary 32 rows, same col)
#pragma unroll
  for (int nf2 = 0; nf2 < 2; ++nf2) {
    float v0 = __shfl_xor(tl[nf2][0], 32);
    float v1 = __shfl_xor(tl[nf2][1], 32);
    float v2 = __shfl_xor(tl[nf2][2], 32);
    float v3 = __shfl_xor(tl[nf2][3], 32);
    float v4 = __shfl_xor(tl[nf2][4], 32);
    INSERT5(tl[nf2][0], tl[nf2][1], tl[nf2][2], tl[nf2][3], tl[nf2][4], v0);
    INSERT5(tl[nf2][0], tl[nf2][1], tl[nf2][2], tl[nf2][3], tl[nf2][4], v1);
    INSERT5(tl[nf2][0], tl[nf2][1], tl[nf2][2], tl[nf2][3], tl[nf2][4], v2);
    INSERT5(tl[nf2][0], tl[nf2][1], tl[nf2][2], tl[nf2][3], tl[nf2][4], v3);
    INSERT5(tl[nf2][0], tl[nf2][1], tl[nf2][2], tl[nf2][3], tl[nf2][4], v4);
  }

  if (lane < 32) {
#pragma unroll
    for (int nf2 = 0; nf2 < 2; ++nf2)
#pragma unroll
      for (int j = 0; j < 5; ++j)
        mbuf[(((wm * 2 + wn) * 2 + nf2) * 32 + lane) * 5 + j] = tl[nf2][j];
  }
  __syncthreads();

  if (tid < 128) {
    int wn2 = tid >> 6, nf2 = (tid >> 5) & 1, q = tid & 31;
    const float* m0 = &mbuf[(((0 * 2 + wn2) * 2 + nf2) * 32 + q) * 5];
    const float* m1 = &mbuf[(((1 * 2 + wn2) * 2 + nf2) * 32 + q) * 5];
    float b0 = m0[0], b1 = m0[1], b2 = m0[2], b3 = m0[3], b4 = m0[4];
#pragma unroll
    for (int j = 0; j < 5; ++j) {
      float v = m1[j];
      INSERT5(b0, b1, b2, b3, b4, v);
    }
    int qgl = q0 + wn2 * 64 + nf2 * 32 + q;
    float sc = sq[qgl];
    float* o = part + ((size_t)qgl * (NPTS / 128) + bm) * KNN;
    o[0] = b0 + sc;   // squared distances; sqrt deferred to k_merge
    o[1] = b1 + sc;
    o[2] = b2 + sc;
    o[3] = b3 + sc;
    o[4] = b4 + sc;
  }

  // ---- row epilogue (off-diagonal blocks): queries = this tile's rows ----
  // pass p = mf2: rows {wm*64 + p*32 + w32} through lsT[128 cols][68 rows].
  if (bm != bn) {
#pragma unroll
    for (int p = 0; p < 2; ++p) {
      __syncthreads();                     // protect mbuf / previous readers
#pragma unroll
      for (int nf2 = 0; nf2 < 2; ++nf2) {
        int cl = wn * 64 + nf2 * 32 + (lane & 31);
#pragma unroll
        for (int q2 = 0; q2 < 4; ++q2) {
          int rl = wm * 32 + q2 * 8 + 4 * lh;
          f32x4 cp;
#pragma unroll
          for (int j = 0; j < 4; ++j)
            cp[j] = fmaf(-2.f, acc[p][nf2][q2 * 4 + j], sqc[nf2]);
          *(f32x4*)&lsT[cl * 68 + rl] = cp;   // 16B-aligned (rl%4==0)
        }
      }
      __syncthreads();
      int r = tid >> 2, qq = tid & 3;        // 4 threads per row, 32 cols each
      float b0 = 1e30f, b1 = 1e30f, b2 = 1e30f, b3 = 1e30f, b4 = 1e30f;
#pragma unroll
      for (int j = 0; j < 32; ++j) {
        int i = (j + 2 * qq) & 31;           // conflict-free read order
        float v = lsT[(qq * 32 + i) * 68 + r];
        INSERT5(b0, b1, b2, b3, b4, v);
      }
#pragma unroll
      for (int m = 1; m <= 2; m <<= 1) {
        float v0 = __shfl_xor(b0, m);
        float v1 = __shfl_xor(b1, m);
        float v2 = __shfl_xor(b2, m);
        float v3 = __shfl_xor(b3, m);
        float v4 = __shfl_xor(b4, m);
        INSERT5(b0, b1, b2, b3, b4, v0);
        INSERT5(b0, b1, b2, b3, b4, v1);
        INSERT5(b0, b1, b2, b3, b4, v2);
        INSERT5(b0, b1, b2, b3, b4, v3);
        INSERT5(b0, b1, b2, b3, b4, v4);
      }
      if ((tid & 3) == 0) {
        int ng = n0 + (r >> 5) * 64 + p * 32 + (r & 31);
        float sn = sq[ng];
        float* o = part + ((size_t)ng * (NPTS / 128) + bn) * KNN;
        o[0] = b0 + sn;   // squared distances
        o[1] = b1 + sn;
        o[2] = b2 + sn;
        o[3] = b3 + sn;
        o[4] = b4 + sn;
      }
    }
  }
}

// ---------------------------------------------------------------------------
// Kernel 2 (fused merge+final): fold 64 partial top-5 (of d^2) per query ->
// (sum, sum2) of distances -> device-scope atomic accumulate; the LAST block
// (atomic ticket) computes -std(knn_dist, ddof=1) and writes out.
__global__ __launch_bounds__(256) void k_merge(const float* __restrict__ part,
                                               double* __restrict__ acc,
                                               u32* __restrict__ cnt,
                                               float* __restrict__ out) {
  __shared__ double red[8];
  int tid = threadIdx.x;
  int q = blockIdx.x * 64 + (tid >> 2);
  int quarter = tid & 3;
  const float4* p =
      (const float4*)(part + ((size_t)q * (NPTS / 128) + quarter * 16) * KNN);
  float b0 = 1e30f, b1 = 1e30f, b2 = 1e30f, b3 = 1e30f, b4 = 1e30f;
#pragma unroll
  for (int i = 0; i < 20; ++i) {
    float4 v = p[i];
    INSERT5(b0, b1, b2, b3, b4, v.x);
    INSERT5(b0, b1, b2, b3, b4, v.y);
    INSERT5(b0, b1, b2, b3, b4, v.z);
    INSERT5(b0, b1, b2, b3, b4, v.w);
  }
#pragma unroll
  for (int m = 1; m <= 2; m <<= 1) {
    float v0 = __shfl_xor(b0, m);
    float v1 = __shfl_xor(b1, m);
    float v2 = __shfl_xor(b2, m);
    float v3 = __shfl_xor(b3, m);
    float v4 = __shfl_xor(b4, m);
    INSERT5(b0, b1, b2, b3, b4, v0);
    INSERT5(b0, b1, b2, b3, b4, v1);
    INSERT5(b0, b1, b2, b3, b4, v2);
    INSERT5(b0, b1, b2, b3, b4, v3);
    INSERT5(b0, b1, b2, b3, b4, v4);
  }
  double ds = 0.0, ds2 = 0.0;
  if ((tid & 3) == 0) {
    float d0 = sqrtf(fmaxf(b0, 0.f));
    float d1 = sqrtf(fmaxf(b1, 0.f));
    float d2 = sqrtf(fmaxf(b2, 0.f));
    float d3 = sqrtf(fmaxf(b3, 0.f));
    float d4 = sqrtf(fmaxf(b4, 0.f));
    float s = d0 + d1 + d2 + d3 + d4;
    float s2 = d0 * d0 + d1 * d1 + d2 * d2 + d3 * d3 + d4 * d4;
    ds = (double)s;
    ds2 = (double)s2;
  }
#pragma unroll
  for (int o = 32; o > 0; o >>= 1) {
    ds += __shfl_down(ds, o);
    ds2 += __shfl_down(ds2, o);
  }
  if ((tid & 63) == 0) {
    red[2 * (tid >> 6)] = ds;
    red[2 * (tid >> 6) + 1] = ds2;
  }
  __syncthreads();
  if (tid == 0) {
    double s = red[0] + red[2] + red[4] + red[6];
    double s2 = red[1] + red[3] + red[5] + red[7];
    atomicAdd(&acc[0], s);
    atomicAdd(&acc[1], s2);
    __threadfence();                         // order acc adds before ticket
    u32 ticket = atomicAdd(cnt, 1u);
    if (ticket == (u32)(gridDim.x - 1)) {    // last block: all adds visible
      __threadfence();
      double S = atomicAdd(&acc[0], 0.0);    // atomic read-back (device-scope)
      double S2 = atomicAdd(&acc[1], 0.0);
      double n = (double)NPTS * (double)KNN;
      double mean = S / n;
      double var = (S2 - n * mean * mean) / (n - 1.0);
      if (var < 0.0) var = 0.0;
      out[0] = -(float)sqrt(var);
    }
  }
}

// ---------------------------------------------------------------------------
extern "C" void kernel_launch(void* const* d_in, const int* in_sizes, int n_in,
                              void* d_out, int out_size, void* d_ws, size_t ws_size,
                              hipStream_t stream) {
  const float* X = (const float*)d_in[0];  // latent[0]
  char* ws = (char*)d_ws;

  // ws: part [8192][64][5] f32 (10.5 MB) | sq [8192] f32 | acc 2xf64 + cnt u32
  //     | Xp8 fp8 packed (4 MB)
  const size_t PART_B = (size_t)NPTS * (NPTS / 128) * KNN * 4;
  float* part = (float*)ws;
  float* sq = (float*)(ws + PART_B);
  double* acc = (double*)(ws + PART_B + 32768);
  u32* cnt = (u32*)(ws + PART_B + 32768 + 16);
  u8* Xp8 = (u8*)(ws + PART_B + 32768 + 2048);
  float* out = (float*)d_out;

  const int NT = NPTS / 128;                       // 64 tiles per dim
  hipLaunchKernelGGL(k_prep, dim3(NPTS / 4), dim3(256), 0, stream, X, Xp8, sq,
                     acc, cnt);
  hipLaunchKernelGGL(k_knn_sym, dim3(NT * (NT + 1) / 2), dim3(256), 0, stream,
                     Xp8, sq, part);
  hipLaunchKernelGGL(k_merge, dim3(NPTS / 64), dim3(256), 0, stream, part,
                     acc, cnt, out);
}

// Round 21
// 53.355 us; speedup vs baseline: 1.0522x; 1.0522x over previous
//
#include <hip/hip_runtime.h>
#include <math.h>

#define NPTS 8192
#define DIM 512
#define KNN 5

typedef unsigned short u16;
typedef unsigned char u8;
typedef unsigned int u32;
typedef __attribute__((ext_vector_type(8))) int i32x8;
typedef __attribute__((ext_vector_type(4))) float f32x4;
typedef __attribute__((ext_vector_type(16))) float f32x16;

// Branch-free sorted insert of v into ascending 5-list.
// Closed form: t_i' = med3(t_{i-1}, t_i, v) (old values), t0' = min(t0, v).
#define INSERT5(t0, t1, t2, t3, t4, v)                \
  do {                                                \
    float _v = (v);                                   \
    float _n4 = __builtin_amdgcn_fmed3f(t3, t4, _v);  \
    float _n3 = __builtin_amdgcn_fmed3f(t2, t3, _v);  \
    float _n2 = __builtin_amdgcn_fmed3f(t1, t2, _v);  \
    float _n1 = __builtin_amdgcn_fmed3f(t0, t1, _v);  \
    t0 = fminf(t0, _v);                               \
    t1 = _n1; t2 = _n2; t3 = _n3; t4 = _n4;           \
  } while (0)

// ---------------------------------------------------------------------------
// Kernel 0: fused fp8-e4m3 convert (to 32x32x64 f8f6f4 MFMA band pack)+sumsq.
// MX fp8 A/B fragment (8 VGPR, 32 B): row = lane&31, k = (lane>>5)*32 + byte
// (32 CONTIGUOUS k-bytes per lane). Band layout (64 rows, byte address):
//   band G = row>>6 (32768 B); iter I = k>>6 (4096 B); mf2 = (row>>5)&1 (2048);
//   frag_lane = ((k>>5)&1)*32 + (row&31) (32 B); byte = k&31.
__global__ __launch_bounds__(256) void k_prep(const float* __restrict__ X,
                                              u8* __restrict__ Xp8,
                                              float* __restrict__ sq) {
  int gt = blockIdx.x * 256 + threadIdx.x;
  int row = gt >> 6;
  int lane = gt & 63;   // holds k = lane*8 .. lane*8+7 (one 8-byte octet)
  const float* r = X + (size_t)row * DIM + lane * 8;
  float4 a = *(const float4*)r;
  float4 b = *(const float4*)(r + 4);
  float s = a.x * a.x + a.y * a.y + a.z * a.z + a.w * a.w
          + b.x * b.x + b.y * b.y + b.z * b.z + b.w * b.w;
  u32 w0 = __builtin_amdgcn_cvt_pk_fp8_f32(a.x, a.y, 0u, false);
  w0 = __builtin_amdgcn_cvt_pk_fp8_f32(a.z, a.w, w0, true);
  u32 w1 = __builtin_amdgcn_cvt_pk_fp8_f32(b.x, b.y, 0u, false);
  w1 = __builtin_amdgcn_cvt_pk_fp8_f32(b.z, b.w, w1, true);
  // k0 = lane*8: iter = lane>>3; kb = (lane&7)*8; kb>>5 = (lane>>2)&1;
  // byte = kb&31 = (lane&3)*8
  u32 dst = (u32)((row >> 6) * 32768 + (lane >> 3) * 4096 +
                  ((row >> 5) & 1) * 2048 +
                  (((lane >> 2) & 1) * 32 + (row & 31)) * 32 + (lane & 3) * 8);
  *(uint2*)(Xp8 + dst) = make_uint2(w0, w1);
#pragma unroll
  for (int o = 32; o > 0; o >>= 1) s += __shfl_down(s, o);
  if (lane == 0) sq[row] = s;
}

// ---------------------------------------------------------------------------
// Kernel 1: symmetric MX-fp8 32x32x64 MFMA distance tiles, triangular grid.
// R18 config (best measured: 40.6/52.7 us) with the setprio pair REMOVED
// (single-variable A/B; T5/m190: setprio is null-to-negative without wave
// role diversity). Flatmm dbuf prefetch, 8x8 super-tile L2 locality.
// C/D: col=lane&31, row=(reg&3)+8*(reg>>2)+4*(lane>>5). part holds d^2.
__global__ __launch_bounds__(256, 3) void k_knn_sym(
    const u8* __restrict__ Xp8, const float* __restrict__ sq,
    float* __restrict__ part) {
  __shared__ __align__(16) char smem[34816];
  float* mbuf = (float*)smem;             // col-epi merge: [wm*2+wn][nf2][32][5]
  float* lsT = (float*)smem;              // row-epi transpose: [128 cols][68]

  const int tid = threadIdx.x;
  const int lane = tid & 63;
  const int wid = tid >> 6;
  const int wm = wid >> 1;
  const int wn = wid & 1;
  const int lh = lane >> 5;               // row-half selector for C/D

  // XCD-aware bijective remap (2080 = 8 * 260) -> 8x8 super-tiles per XCD
  int t = (blockIdx.x & 7) * 260 + (blockIdx.x >> 3);
  int bm, bn;
  if (t < 1792) {
    int st = t >> 6, u = t & 63;
    int SM = (int)((sqrtf(8.f * st + 1.f) + 1.f) * 0.5f);
    while (SM * (SM - 1) / 2 > st) --SM;
    while ((SM + 1) * SM / 2 <= st) ++SM;
    int SN = st - SM * (SM - 1) / 2;
    bm = SM * 8 + (u >> 3);
    bn = SN * 8 + (u & 7);
  } else {
    int d = t - 1792;
    int SM = d / 36, u = d % 36;
    int im = (int)((sqrtf(8.f * u + 1.f) - 1.f) * 0.5f);
    while ((im + 1) * (im + 2) / 2 <= u) ++im;
    while (im * (im + 1) / 2 > u) --im;
    int in = u - im * (im + 1) / 2;
    bm = SM * 8 + im;
    bn = SM * 8 + in;
  }
  const int n0 = bm * 128;
  const int q0 = bn * 128;

  // Band pointers: band (64 rows) = 32768 B; advance 4096 B per K-64 iter.
  const u8* pa = Xp8 + (size_t)(bm * 2 + wm) * 32768 + lane * 32;
  const u8* pb = Xp8 + (size_t)(bn * 2 + wn) * 32768 + lane * 32;

  // 32B fragment load = two dwordx4
#define LD32(dst, p)                                           \
  do {                                                         \
    uint4 _lo = *(const uint4*)(p);                            \
    uint4 _hi = *(const uint4*)((p) + 16);                     \
    dst[0] = (int)_lo.x; dst[1] = (int)_lo.y;                  \
    dst[2] = (int)_lo.z; dst[3] = (int)_lo.w;                  \
    dst[4] = (int)_hi.x; dst[5] = (int)_hi.y;                  \
    dst[6] = (int)_hi.z; dst[7] = (int)_hi.w;                  \
  } while (0)

  i32x8 afr[2][2], bfr[2][2];             // [buf][mf2/nf2]
#define LOADF(buf)                                             \
  do {                                                         \
    LD32(afr[buf][0], pa);                                     \
    LD32(afr[buf][1], pa + 2048);                              \
    LD32(bfr[buf][0], pb);                                     \
    LD32(bfr[buf][1], pb + 2048);                              \
  } while (0)

  f32x16 acc[2][2];
#pragma unroll
  for (int mf2 = 0; mf2 < 2; ++mf2)
#pragma unroll
    for (int nf2 = 0; nf2 < 2; ++nf2)
#pragma unroll
      for (int r = 0; r < 16; ++r) acc[mf2][nf2][r] = 0.f;

  LOADF(0);

#pragma unroll
  for (int step = 0; step < DIM / 64; ++step) {        // 8 iters of K=64
    const int cur = step & 1;
    if (step < DIM / 64 - 1) {
      pa += 4096;
      pb += 4096;
      LOADF(cur ^ 1);                                  // prefetch next iter
    }
    __builtin_amdgcn_sched_barrier(0);
#pragma unroll
    for (int mf2 = 0; mf2 < 2; ++mf2)
#pragma unroll
      for (int nf2 = 0; nf2 < 2; ++nf2)
        acc[mf2][nf2] = __builtin_amdgcn_mfma_scale_f32_32x32x64_f8f6f4(
            afr[cur][mf2], bfr[cur][nf2], acc[mf2][nf2],
            0, 0,            // cbsz/blgp: fp8 e4m3 / fp8 e4m3
            0, 127,          // scale A: opsel 0, e8m0 127 = 1.0
            0, 127);         // scale B: opsel 0, e8m0 127 = 1.0
  }
#undef LOADF
#undef LD32

  // ---- column epilogue: per query-col top-5 of (sq_row - 2*dot) ----
  int qg[2];
  float sqc[2];
#pragma unroll
  for (int nf2 = 0; nf2 < 2; ++nf2) {
    qg[nf2] = q0 + wn * 64 + nf2 * 32 + (lane & 31);
    sqc[nf2] = sq[qg[nf2]];
  }

  float tl[2][5];
#pragma unroll
  for (int nf2 = 0; nf2 < 2; ++nf2)
#pragma unroll
    for (int j = 0; j < 5; ++j) tl[nf2][j] = 1e30f;

  // diagonal mask needed only on the 64 diagonal tiles (uniform branch)
#define COLSCAN(DIAG)                                                         \
  do {                                                                        \
    _Pragma("unroll")                                                         \
    for (int mf2 = 0; mf2 < 2; ++mf2) {                                       \
      _Pragma("unroll")                                                       \
      for (int q2 = 0; q2 < 4; ++q2) {                                        \
        int ngb = n0 + wm * 64 + mf2 * 32 + q2 * 8 + 4 * lh;                  \
        float4 snv = *(const float4*)&sq[ngb];                                \
        _Pragma("unroll")                                                     \
        for (int j = 0; j < 4; ++j) {                                         \
          float sn = (j == 0) ? snv.x : (j == 1) ? snv.y                      \
                   : (j == 2) ? snv.z : snv.w;                                \
          _Pragma("unroll")                                                   \
          for (int nf2 = 0; nf2 < 2; ++nf2) {                                 \
            float c = fmaf(-2.f, acc[mf2][nf2][q2 * 4 + j], sn);              \
            if (DIAG) c = ((ngb + j) == qg[nf2]) ? -1e30f : c;                \
            INSERT5(tl[nf2][0], tl[nf2][1], tl[nf2][2], tl[nf2][3],           \
                    tl[nf2][4], c);                                           \
          }                                                                   \
        }                                                                     \
      }                                                                       \
    }                                                                         \
  } while (0)

  if (bm == bn) COLSCAN(true); else COLSCAN(false);
#undef COLSCAN

  // merge with partner lane^32 (holds the complementary 32 rows, same col)
#pragma unroll
  for (int nf2 = 0; nf2 < 2; ++nf2) {
    float v0 = __shfl_xor(tl[nf2][0], 32);
    float v1 = __shfl_xor(tl[nf2][1], 32);
    float v2 = __shfl_xor(tl[nf2][2], 32);
    float v3 = __shfl_xor(tl[nf2][3], 32);
    float v4 = __shfl_xor(tl[nf2][4], 32);
    INSERT5(tl[nf2][0], tl[nf2][1], tl[nf2][2], tl[nf2][3], tl[nf2][4], v0);
    INSERT5(tl[nf2][0], tl[nf2][1], tl[nf2][2], tl[nf2][3], tl[nf2][4], v1);
    INSERT5(tl[nf2][0], tl[nf2][1], tl[nf2][2], tl[nf2][3], tl[nf2][4], v2);
    INSERT5(tl[nf2][0], tl[nf2][1], tl[nf2][2], tl[nf2][3], tl[nf2][4], v3);
    INSERT5(tl[nf2][0], tl[nf2][1], tl[nf2][2], tl[nf2][3], tl[nf2][4], v4);
  }

  if (lane < 32) {
#pragma unroll
    for (int nf2 = 0; nf2 < 2; ++nf2)
#pragma unroll
      for (int j = 0; j < 5; ++j)
        mbuf[(((wm * 2 + wn) * 2 + nf2) * 32 + lane) * 5 + j] = tl[nf2][j];
  }
  __syncthreads();

  if (tid < 128) {
    int wn2 = tid >> 6, nf2 = (tid >> 5) & 1, q = tid & 31;
    const float* m0 = &mbuf[(((0 * 2 + wn2) * 2 + nf2) * 32 + q) * 5];
    const float* m1 = &mbuf[(((1 * 2 + wn2) * 2 + nf2) * 32 + q) * 5];
    float b0 = m0[0], b1 = m0[1], b2 = m0[2], b3 = m0[3], b4 = m0[4];
#pragma unroll
    for (int j = 0; j < 5; ++j) {
      float v = m1[j];
      INSERT5(b0, b1, b2, b3, b4, v);
    }
    int qgl = q0 + wn2 * 64 + nf2 * 32 + q;
    float sc = sq[qgl];
    float* o = part + ((size_t)qgl * (NPTS / 128) + bm) * KNN;
    o[0] = b0 + sc;   // squared distances; sqrt deferred to k_merge
    o[1] = b1 + sc;
    o[2] = b2 + sc;
    o[3] = b3 + sc;
    o[4] = b4 + sc;
  }

  // ---- row epilogue (off-diagonal blocks): queries = this tile's rows ----
  // pass p = mf2: rows {wm*64 + p*32 + w32} through lsT[128 cols][68 rows].
  if (bm != bn) {
#pragma unroll
    for (int p = 0; p < 2; ++p) {
      __syncthreads();                     // protect mbuf / previous readers
#pragma unroll
      for (int nf2 = 0; nf2 < 2; ++nf2) {
        int cl = wn * 64 + nf2 * 32 + (lane & 31);
#pragma unroll
        for (int q2 = 0; q2 < 4; ++q2) {
          int rl = wm * 32 + q2 * 8 + 4 * lh;
          f32x4 cp;
#pragma unroll
          for (int j = 0; j < 4; ++j)
            cp[j] = fmaf(-2.f, acc[p][nf2][q2 * 4 + j], sqc[nf2]);
          *(f32x4*)&lsT[cl * 68 + rl] = cp;   // 16B-aligned (rl%4==0)
        }
      }
      __syncthreads();
      int r = tid >> 2, qq = tid & 3;        // 4 threads per row, 32 cols each
      float b0 = 1e30f, b1 = 1e30f, b2 = 1e30f, b3 = 1e30f, b4 = 1e30f;
#pragma unroll
      for (int j = 0; j < 32; ++j) {
        int i = (j + 2 * qq) & 31;           // conflict-free read order
        float v = lsT[(qq * 32 + i) * 68 + r];
        INSERT5(b0, b1, b2, b3, b4, v);
      }
#pragma unroll
      for (int m = 1; m <= 2; m <<= 1) {
        float v0 = __shfl_xor(b0, m);
        float v1 = __shfl_xor(b1, m);
        float v2 = __shfl_xor(b2, m);
        float v3 = __shfl_xor(b3, m);
        float v4 = __shfl_xor(b4, m);
        INSERT5(b0, b1, b2, b3, b4, v0);
        INSERT5(b0, b1, b2, b3, b4, v1);
        INSERT5(b0, b1, b2, b3, b4, v2);
        INSERT5(b0, b1, b2, b3, b4, v3);
        INSERT5(b0, b1, b2, b3, b4, v4);
      }
      if ((tid & 3) == 0) {
        int ng = n0 + (r >> 5) * 64 + p * 32 + (r & 31);
        float sn = sq[ng];
        float* o = part + ((size_t)ng * (NPTS / 128) + bn) * KNN;
        o[0] = b0 + sn;   // squared distances
        o[1] = b1 + sn;
        o[2] = b2 + sn;
        o[3] = b3 + sn;
        o[4] = b4 + sn;
      }
    }
  }
}

// ---------------------------------------------------------------------------
// Kernel 2: fold 64 partial top-5 (of d^2) per query -> per-block (sum, sum2)
// of DISTANCES (sqrt applied to the final 5 only).
__global__ __launch_bounds__(256) void k_merge(const float* __restrict__ part,
                                               double* __restrict__ pacc) {
  __shared__ double red[8];
  int tid = threadIdx.x;
  int q = blockIdx.x * 64 + (tid >> 2);
  int quarter = tid & 3;
  const float4* p =
      (const float4*)(part + ((size_t)q * (NPTS / 128) + quarter * 16) * KNN);
  float b0 = 1e30f, b1 = 1e30f, b2 = 1e30f, b3 = 1e30f, b4 = 1e30f;
#pragma unroll
  for (int i = 0; i < 20; ++i) {
    float4 v = p[i];
    INSERT5(b0, b1, b2, b3, b4, v.x);
    INSERT5(b0, b1, b2, b3, b4, v.y);
    INSERT5(b0, b1, b2, b3, b4, v.z);
    INSERT5(b0, b1, b2, b3, b4, v.w);
  }
#pragma unroll
  for (int m = 1; m <= 2; m <<= 1) {
    float v0 = __shfl_xor(b0, m);
    float v1 = __shfl_xor(b1, m);
    float v2 = __shfl_xor(b2, m);
    float v3 = __shfl_xor(b3, m);
    float v4 = __shfl_xor(b4, m);
    INSERT5(b0, b1, b2, b3, b4, v0);
    INSERT5(b0, b1, b2, b3, b4, v1);
    INSERT5(b0, b1, b2, b3, b4, v2);
    INSERT5(b0, b1, b2, b3, b4, v3);
    INSERT5(b0, b1, b2, b3, b4, v4);
  }
  double ds = 0.0, ds2 = 0.0;
  if ((tid & 3) == 0) {
    float d0 = sqrtf(fmaxf(b0, 0.f));
    float d1 = sqrtf(fmaxf(b1, 0.f));
    float d2 = sqrtf(fmaxf(b2, 0.f));
    float d3 = sqrtf(fmaxf(b3, 0.f));
    float d4 = sqrtf(fmaxf(b4, 0.f));
    float s = d0 + d1 + d2 + d3 + d4;
    float s2 = d0 * d0 + d1 * d1 + d2 * d2 + d3 * d3 + d4 * d4;
    ds = (double)s;
    ds2 = (double)s2;
  }
#pragma unroll
  for (int o = 32; o > 0; o >>= 1) {
    ds += __shfl_down(ds, o);
    ds2 += __shfl_down(ds2, o);
  }
  if ((tid & 63) == 0) {
    red[2 * (tid >> 6)] = ds;
    red[2 * (tid >> 6) + 1] = ds2;
  }
  __syncthreads();
  if (tid == 0) {
    double s = red[0] + red[2] + red[4] + red[6];
    double s2 = red[1] + red[3] + red[5] + red[7];
    pacc[2 * blockIdx.x] = s;
    pacc[2 * blockIdx.x + 1] = s2;
  }
}

// Kernel 3: fold 128 block partials -> -std(knn_dist, ddof=1)
__global__ void k_final(const double* __restrict__ pacc, float* __restrict__ out) {
  int lane = threadIdx.x;
  double s = pacc[2 * lane] + pacc[2 * (lane + 64)];
  double s2 = pacc[2 * lane + 1] + pacc[2 * (lane + 64) + 1];
#pragma unroll
  for (int o = 32; o > 0; o >>= 1) {
    s += __shfl_down(s, o);
    s2 += __shfl_down(s2, o);
  }
  if (lane == 0) {
    double n = (double)NPTS * (double)KNN;
    double mean = s / n;
    double var = (s2 - n * mean * mean) / (n - 1.0);
    if (var < 0.0) var = 0.0;
    out[0] = -(float)sqrt(var);
  }
}

// ---------------------------------------------------------------------------
extern "C" void kernel_launch(void* const* d_in, const int* in_sizes, int n_in,
                              void* d_out, int out_size, void* d_ws, size_t ws_size,
                              hipStream_t stream) {
  const float* X = (const float*)d_in[0];  // latent[0]
  char* ws = (char*)d_ws;

  // ws: part [8192][64][5] f32 (10.5 MB) | sq [8192] f32 | pacc [256] f64 | Xp8 fp8 packed (4 MB)
  const size_t PART_B = (size_t)NPTS * (NPTS / 128) * KNN * 4;
  float* part = (float*)ws;
  float* sq = (float*)(ws + PART_B);
  double* pacc = (double*)(ws + PART_B + 32768);
  u8* Xp8 = (u8*)(ws + PART_B + 32768 + 2048);
  float* out = (float*)d_out;

  const int NT = NPTS / 128;                       // 64 tiles per dim
  hipLaunchKernelGGL(k_prep, dim3(NPTS / 4), dim3(256), 0, stream, X, Xp8, sq);
  hipLaunchKernelGGL(k_knn_sym, dim3(NT * (NT + 1) / 2), dim3(256), 0, stream,
                     Xp8, sq, part);
  hipLaunchKernelGGL(k_merge, dim3(NPTS / 64), dim3(256), 0, stream, part, pacc);
  hipLaunchKernelGGL(k_final, dim3(1), dim3(64), 0, stream, pacc, out);
}

// Round 22
// 53.249 us; speedup vs baseline: 1.0543x; 1.0020x over previous
//
#include <hip/hip_runtime.h>
#include <math.h>

#define NPTS 8192
#define DIM 512
#define KNN 5

typedef unsigned short u16;
typedef unsigned char u8;
typedef unsigned int u32;
typedef __attribute__((ext_vector_type(8))) int i32x8;
typedef __attribute__((ext_vector_type(4))) float f32x4;
typedef __attribute__((ext_vector_type(16))) float f32x16;

// Branch-free sorted insert of v into ascending 5-list.
// Closed form: t_i' = med3(t_{i-1}, t_i, v) (old values), t0' = min(t0, v).
#define INSERT5(t0, t1, t2, t3, t4, v)                \
  do {                                                \
    float _v = (v);                                   \
    float _n4 = __builtin_amdgcn_fmed3f(t3, t4, _v);  \
    float _n3 = __builtin_amdgcn_fmed3f(t2, t3, _v);  \
    float _n2 = __builtin_amdgcn_fmed3f(t1, t2, _v);  \
    float _n1 = __builtin_amdgcn_fmed3f(t0, t1, _v);  \
    t0 = fminf(t0, _v);                               \
    t1 = _n1; t2 = _n2; t3 = _n3; t4 = _n4;           \
  } while (0)

// ---------------------------------------------------------------------------
// Kernel 0: fused fp8-e4m3 convert (to 32x32x64 f8f6f4 MFMA band pack)+sumsq.
// MX fp8 A/B fragment (8 VGPR, 32 B): row = lane&31, k = (lane>>5)*32 + byte
// (32 CONTIGUOUS k-bytes per lane). Band layout (64 rows, byte address):
//   band G = row>>6 (32768 B); iter I = k>>6 (4096 B); mf2 = (row>>5)&1 (2048);
//   frag_lane = ((k>>5)&1)*32 + (row&31) (32 B); byte = k&31.
__global__ __launch_bounds__(256) void k_prep(const float* __restrict__ X,
                                              u8* __restrict__ Xp8,
                                              float* __restrict__ sq) {
  int gt = blockIdx.x * 256 + threadIdx.x;
  int row = gt >> 6;
  int lane = gt & 63;   // holds k = lane*8 .. lane*8+7 (one 8-byte octet)
  const float* r = X + (size_t)row * DIM + lane * 8;
  float4 a = *(const float4*)r;
  float4 b = *(const float4*)(r + 4);
  float s = a.x * a.x + a.y * a.y + a.z * a.z + a.w * a.w
          + b.x * b.x + b.y * b.y + b.z * b.z + b.w * b.w;
  u32 w0 = __builtin_amdgcn_cvt_pk_fp8_f32(a.x, a.y, 0u, false);
  w0 = __builtin_amdgcn_cvt_pk_fp8_f32(a.z, a.w, w0, true);
  u32 w1 = __builtin_amdgcn_cvt_pk_fp8_f32(b.x, b.y, 0u, false);
  w1 = __builtin_amdgcn_cvt_pk_fp8_f32(b.z, b.w, w1, true);
  // k0 = lane*8: iter = lane>>3; kb = (lane&7)*8; kb>>5 = (lane>>2)&1;
  // byte = kb&31 = (lane&3)*8
  u32 dst = (u32)((row >> 6) * 32768 + (lane >> 3) * 4096 +
                  ((row >> 5) & 1) * 2048 +
                  (((lane >> 2) & 1) * 32 + (row & 31)) * 32 + (lane & 3) * 8);
  *(uint2*)(Xp8 + dst) = make_uint2(w0, w1);
#pragma unroll
  for (int o = 32; o > 0; o >>= 1) s += __shfl_down(s, o);
  if (lane == 0) sq[row] = s;
}

// ---------------------------------------------------------------------------
// Kernel 1: symmetric MX-fp8 32x32x64 MFMA distance tiles, triangular grid.
// R21 config with ONE change: fragments loaded DIRECTLY as i32x8 (32B vector
// load -> 2x global_load_dwordx4 into the 8 consecutive VGPRs) instead of the
// element-wise uint4 unpack (which cost up to 8 v_mov_b32 per fragment,
// ~256 junk VALU instrs/wave in the K-loop). Flatmm dbuf prefetch, 8x8
// super-tile L2 locality. C/D: col=lane&31, row=(reg&3)+8*(reg>>2)+4*(lane>>5).
// part holds SQUARED distances (sqrt deferred to k_merge).
__global__ __launch_bounds__(256, 3) void k_knn_sym(
    const u8* __restrict__ Xp8, const float* __restrict__ sq,
    float* __restrict__ part) {
  __shared__ __align__(16) char smem[34816];
  float* mbuf = (float*)smem;             // col-epi merge: [wm*2+wn][nf2][32][5]
  float* lsT = (float*)smem;              // row-epi transpose: [128 cols][68]

  const int tid = threadIdx.x;
  const int lane = tid & 63;
  const int wid = tid >> 6;
  const int wm = wid >> 1;
  const int wn = wid & 1;
  const int lh = lane >> 5;               // row-half selector for C/D

  // XCD-aware bijective remap (2080 = 8 * 260) -> 8x8 super-tiles per XCD
  int t = (blockIdx.x & 7) * 260 + (blockIdx.x >> 3);
  int bm, bn;
  if (t < 1792) {
    int st = t >> 6, u = t & 63;
    int SM = (int)((sqrtf(8.f * st + 1.f) + 1.f) * 0.5f);
    while (SM * (SM - 1) / 2 > st) --SM;
    while ((SM + 1) * SM / 2 <= st) ++SM;
    int SN = st - SM * (SM - 1) / 2;
    bm = SM * 8 + (u >> 3);
    bn = SN * 8 + (u & 7);
  } else {
    int d = t - 1792;
    int SM = d / 36, u = d % 36;
    int im = (int)((sqrtf(8.f * u + 1.f) - 1.f) * 0.5f);
    while ((im + 1) * (im + 2) / 2 <= u) ++im;
    while (im * (im + 1) / 2 > u) --im;
    int in = u - im * (im + 1) / 2;
    bm = SM * 8 + im;
    bn = SM * 8 + in;
  }
  const int n0 = bm * 128;
  const int q0 = bn * 128;

  // Band pointers: band (64 rows) = 32768 B; advance 4096 B per K-64 iter.
  // 32B-aligned (lane*32), so i32x8 vector loads are legal.
  const u8* pa = Xp8 + (size_t)(bm * 2 + wm) * 32768 + lane * 32;
  const u8* pb = Xp8 + (size_t)(bn * 2 + wn) * 32768 + lane * 32;

  i32x8 afr[2][2], bfr[2][2];             // [buf][mf2/nf2]
#define LOADF(buf)                                             \
  do {                                                         \
    afr[buf][0] = *(const i32x8*)(pa);                         \
    afr[buf][1] = *(const i32x8*)(pa + 2048);                  \
    bfr[buf][0] = *(const i32x8*)(pb);                         \
    bfr[buf][1] = *(const i32x8*)(pb + 2048);                  \
  } while (0)

  f32x16 acc[2][2];
#pragma unroll
  for (int mf2 = 0; mf2 < 2; ++mf2)
#pragma unroll
    for (int nf2 = 0; nf2 < 2; ++nf2)
#pragma unroll
      for (int r = 0; r < 16; ++r) acc[mf2][nf2][r] = 0.f;

  LOADF(0);

#pragma unroll
  for (int step = 0; step < DIM / 64; ++step) {        // 8 iters of K=64
    const int cur = step & 1;
    if (step < DIM / 64 - 1) {
      pa += 4096;
      pb += 4096;
      LOADF(cur ^ 1);                                  // prefetch next iter
    }
    __builtin_amdgcn_sched_barrier(0);
#pragma unroll
    for (int mf2 = 0; mf2 < 2; ++mf2)
#pragma unroll
      for (int nf2 = 0; nf2 < 2; ++nf2)
        acc[mf2][nf2] = __builtin_amdgcn_mfma_scale_f32_32x32x64_f8f6f4(
            afr[cur][mf2], bfr[cur][nf2], acc[mf2][nf2],
            0, 0,            // cbsz/blgp: fp8 e4m3 / fp8 e4m3
            0, 127,          // scale A: opsel 0, e8m0 127 = 1.0
            0, 127);         // scale B: opsel 0, e8m0 127 = 1.0
  }
#undef LOADF

  // ---- column epilogue: per query-col top-5 of (sq_row - 2*dot) ----
  int qg[2];
  float sqc[2];
#pragma unroll
  for (int nf2 = 0; nf2 < 2; ++nf2) {
    qg[nf2] = q0 + wn * 64 + nf2 * 32 + (lane & 31);
    sqc[nf2] = sq[qg[nf2]];
  }

  float tl[2][5];
#pragma unroll
  for (int nf2 = 0; nf2 < 2; ++nf2)
#pragma unroll
    for (int j = 0; j < 5; ++j) tl[nf2][j] = 1e30f;

  // diagonal mask needed only on the 64 diagonal tiles (uniform branch)
#define COLSCAN(DIAG)                                                         \
  do {                                                                        \
    _Pragma("unroll")                                                         \
    for (int mf2 = 0; mf2 < 2; ++mf2) {                                       \
      _Pragma("unroll")                                                       \
      for (int q2 = 0; q2 < 4; ++q2) {                                        \
        int ngb = n0 + wm * 64 + mf2 * 32 + q2 * 8 + 4 * lh;                  \
        float4 snv = *(const float4*)&sq[ngb];                                \
        _Pragma("unroll")                                                     \
        for (int j = 0; j < 4; ++j) {                                         \
          float sn = (j == 0) ? snv.x : (j == 1) ? snv.y                      \
                   : (j == 2) ? snv.z : snv.w;                                \
          _Pragma("unroll")                                                   \
          for (int nf2 = 0; nf2 < 2; ++nf2) {                                 \
            float c = fmaf(-2.f, acc[mf2][nf2][q2 * 4 + j], sn);              \
            if (DIAG) c = ((ngb + j) == qg[nf2]) ? -1e30f : c;                \
            INSERT5(tl[nf2][0], tl[nf2][1], tl[nf2][2], tl[nf2][3],           \
                    tl[nf2][4], c);                                           \
          }                                                                   \
        }                                                                     \
      }                                                                       \
    }                                                                         \
  } while (0)

  if (bm == bn) COLSCAN(true); else COLSCAN(false);
#undef COLSCAN

  // merge with partner lane^32 (holds the complementary 32 rows, same col)
#pragma unroll
  for (int nf2 = 0; nf2 < 2; ++nf2) {
    float v0 = __shfl_xor(tl[nf2][0], 32);
    float v1 = __shfl_xor(tl[nf2][1], 32);
    float v2 = __shfl_xor(tl[nf2][2], 32);
    float v3 = __shfl_xor(tl[nf2][3], 32);
    float v4 = __shfl_xor(tl[nf2][4], 32);
    INSERT5(tl[nf2][0], tl[nf2][1], tl[nf2][2], tl[nf2][3], tl[nf2][4], v0);
    INSERT5(tl[nf2][0], tl[nf2][1], tl[nf2][2], tl[nf2][3], tl[nf2][4], v1);
    INSERT5(tl[nf2][0], tl[nf2][1], tl[nf2][2], tl[nf2][3], tl[nf2][4], v2);
    INSERT5(tl[nf2][0], tl[nf2][1], tl[nf2][2], tl[nf2][3], tl[nf2][4], v3);
    INSERT5(tl[nf2][0], tl[nf2][1], tl[nf2][2], tl[nf2][3], tl[nf2][4], v4);
  }

  if (lane < 32) {
#pragma unroll
    for (int nf2 = 0; nf2 < 2; ++nf2)
#pragma unroll
      for (int j = 0; j < 5; ++j)
        mbuf[(((wm * 2 + wn) * 2 + nf2) * 32 + lane) * 5 + j] = tl[nf2][j];
  }
  __syncthreads();

  if (tid < 128) {
    int wn2 = tid >> 6, nf2 = (tid >> 5) & 1, q = tid & 31;
    const float* m0 = &mbuf[(((0 * 2 + wn2) * 2 + nf2) * 32 + q) * 5];
    const float* m1 = &mbuf[(((1 * 2 + wn2) * 2 + nf2) * 32 + q) * 5];
    float b0 = m0[0], b1 = m0[1], b2 = m0[2], b3 = m0[3], b4 = m0[4];
#pragma unroll
    for (int j = 0; j < 5; ++j) {
      float v = m1[j];
      INSERT5(b0, b1, b2, b3, b4, v);
    }
    int qgl = q0 + wn2 * 64 + nf2 * 32 + q;
    float sc = sq[qgl];
    float* o = part + ((size_t)qgl * (NPTS / 128) + bm) * KNN;
    o[0] = b0 + sc;   // squared distances; sqrt deferred to k_merge
    o[1] = b1 + sc;
    o[2] = b2 + sc;
    o[3] = b3 + sc;
    o[4] = b4 + sc;
  }

  // ---- row epilogue (off-diagonal blocks): queries = this tile's rows ----
  // pass p = mf2: rows {wm*64 + p*32 + w32} through lsT[128 cols][68 rows].
  if (bm != bn) {
#pragma unroll
    for (int p = 0; p < 2; ++p) {
      __syncthreads();                     // protect mbuf / previous readers
#pragma unroll
      for (int nf2 = 0; nf2 < 2; ++nf2) {
        int cl = wn * 64 + nf2 * 32 + (lane & 31);
#pragma unroll
        for (int q2 = 0; q2 < 4; ++q2) {
          int rl = wm * 32 + q2 * 8 + 4 * lh;
          f32x4 cp;
#pragma unroll
          for (int j = 0; j < 4; ++j)
            cp[j] = fmaf(-2.f, acc[p][nf2][q2 * 4 + j], sqc[nf2]);
          *(f32x4*)&lsT[cl * 68 + rl] = cp;   // 16B-aligned (rl%4==0)
        }
      }
      __syncthreads();
      int r = tid >> 2, qq = tid & 3;        // 4 threads per row, 32 cols each
      float b0 = 1e30f, b1 = 1e30f, b2 = 1e30f, b3 = 1e30f, b4 = 1e30f;
#pragma unroll
      for (int j = 0; j < 32; ++j) {
        int i = (j + 2 * qq) & 31;           // conflict-free read order
        float v = lsT[(qq * 32 + i) * 68 + r];
        INSERT5(b0, b1, b2, b3, b4, v);
      }
#pragma unroll
      for (int m = 1; m <= 2; m <<= 1) {
        float v0 = __shfl_xor(b0, m);
        float v1 = __shfl_xor(b1, m);
        float v2 = __shfl_xor(b2, m);
        float v3 = __shfl_xor(b3, m);
        float v4 = __shfl_xor(b4, m);
        INSERT5(b0, b1, b2, b3, b4, v0);
        INSERT5(b0, b1, b2, b3, b4, v1);
        INSERT5(b0, b1, b2, b3, b4, v2);
        INSERT5(b0, b1, b2, b3, b4, v3);
        INSERT5(b0, b1, b2, b3, b4, v4);
      }
      if ((tid & 3) == 0) {
        int ng = n0 + (r >> 5) * 64 + p * 32 + (r & 31);
        float sn = sq[ng];
        float* o = part + ((size_t)ng * (NPTS / 128) + bn) * KNN;
        o[0] = b0 + sn;   // squared distances
        o[1] = b1 + sn;
        o[2] = b2 + sn;
        o[3] = b3 + sn;
        o[4] = b4 + sn;
      }
    }
  }
}

// ---------------------------------------------------------------------------
// Kernel 2: fold 64 partial top-5 (of d^2) per query -> per-block (sum, sum2)
// of DISTANCES (sqrt applied to the final 5 only).
__global__ __launch_bounds__(256) void k_merge(const float* __restrict__ part,
                                               double* __restrict__ pacc) {
  __shared__ double red[8];
  int tid = threadIdx.x;
  int q = blockIdx.x * 64 + (tid >> 2);
  int quarter = tid & 3;
  const float4* p =
      (const float4*)(part + ((size_t)q * (NPTS / 128) + quarter * 16) * KNN);
  float b0 = 1e30f, b1 = 1e30f, b2 = 1e30f, b3 = 1e30f, b4 = 1e30f;
#pragma unroll
  for (int i = 0; i < 20; ++i) {
    float4 v = p[i];
    INSERT5(b0, b1, b2, b3, b4, v.x);
    INSERT5(b0, b1, b2, b3, b4, v.y);
    INSERT5(b0, b1, b2, b3, b4, v.z);
    INSERT5(b0, b1, b2, b3, b4, v.w);
  }
#pragma unroll
  for (int m = 1; m <= 2; m <<= 1) {
    float v0 = __shfl_xor(b0, m);
    float v1 = __shfl_xor(b1, m);
    float v2 = __shfl_xor(b2, m);
    float v3 = __shfl_xor(b3, m);
    float v4 = __shfl_xor(b4, m);
    INSERT5(b0, b1, b2, b3, b4, v0);
    INSERT5(b0, b1, b2, b3, b4, v1);
    INSERT5(b0, b1, b2, b3, b4, v2);
    INSERT5(b0, b1, b2, b3, b4, v3);
    INSERT5(b0, b1, b2, b3, b4, v4);
  }
  double ds = 0.0, ds2 = 0.0;
  if ((tid & 3) == 0) {
    float d0 = sqrtf(fmaxf(b0, 0.f));
    float d1 = sqrtf(fmaxf(b1, 0.f));
    float d2 = sqrtf(fmaxf(b2, 0.f));
    float d3 = sqrtf(fmaxf(b3, 0.f));
    float d4 = sqrtf(fmaxf(b4, 0.f));
    float s = d0 + d1 + d2 + d3 + d4;
    float s2 = d0 * d0 + d1 * d1 + d2 * d2 + d3 * d3 + d4 * d4;
    ds = (double)s;
    ds2 = (double)s2;
  }
#pragma unroll
  for (int o = 32; o > 0; o >>= 1) {
    ds += __shfl_down(ds, o);
    ds2 += __shfl_down(ds2, o);
  }
  if ((tid & 63) == 0) {
    red[2 * (tid >> 6)] = ds;
    red[2 * (tid >> 6) + 1] = ds2;
  }
  __syncthreads();
  if (tid == 0) {
    double s = red[0] + red[2] + red[4] + red[6];
    double s2 = red[1] + red[3] + red[5] + red[7];
    pacc[2 * blockIdx.x] = s;
    pacc[2 * blockIdx.x + 1] = s2;
  }
}

// Kernel 3: fold 128 block partials -> -std(knn_dist, ddof=1)
__global__ void k_final(const double* __restrict__ pacc, float* __restrict__ out) {
  int lane = threadIdx.x;
  double s = pacc[2 * lane] + pacc[2 * (lane + 64)];
  double s2 = pacc[2 * lane + 1] + pacc[2 * (lane + 64) + 1];
#pragma unroll
  for (int o = 32; o > 0; o >>= 1) {
    s += __shfl_down(s, o);
    s2 += __shfl_down(s2, o);
  }
  if (lane == 0) {
    double n = (double)NPTS * (double)KNN;
    double mean = s / n;
    double var = (s2 - n * mean * mean) / (n - 1.0);
    if (var < 0.0) var = 0.0;
    out[0] = -(float)sqrt(var);
  }
}

// ---------------------------------------------------------------------------
extern "C" void kernel_launch(void* const* d_in, const int* in_sizes, int n_in,
                              void* d_out, int out_size, void* d_ws, size_t ws_size,
                              hipStream_t stream) {
  const float* X = (const float*)d_in[0];  // latent[0]
  char* ws = (char*)d_ws;

  // ws: part [8192][64][5] f32 (10.5 MB) | sq [8192] f32 | pacc [256] f64 | Xp8 fp8 packed (4 MB)
  const size_t PART_B = (size_t)NPTS * (NPTS / 128) * KNN * 4;
  float* part = (float*)ws;
  float* sq = (float*)(ws + PART_B);
  double* pacc = (double*)(ws + PART_B + 32768);
  u8* Xp8 = (u8*)(ws + PART_B + 32768 + 2048);
  float* out = (float*)d_out;

  const int NT = NPTS / 128;                       // 64 tiles per dim
  hipLaunchKernelGGL(k_prep, dim3(NPTS / 4), dim3(256), 0, stream, X, Xp8, sq);
  hipLaunchKernelGGL(k_knn_sym, dim3(NT * (NT + 1) / 2), dim3(256), 0, stream,
                     Xp8, sq, part);
  hipLaunchKernelGGL(k_merge, dim3(NPTS / 64), dim3(256), 0, stream, part, pacc);
  hipLaunchKernelGGL(k_final, dim3(1), dim3(64), 0, stream, pacc, out);
}

// Round 23
// 45.983 us; speedup vs baseline: 1.2209x; 1.1580x over previous
//
#include <hip/hip_runtime.h>
#include <math.h>

#define NPTS 8192
#define DIM 512
#define KNN 5

typedef unsigned short u16;
typedef unsigned char u8;
typedef unsigned int u32;
typedef __attribute__((ext_vector_type(4))) int i32x4;
typedef __attribute__((ext_vector_type(8))) int i32x8;
typedef __attribute__((ext_vector_type(4))) float f32x4;
typedef __attribute__((ext_vector_type(16))) float f32x16;

// Branch-free sorted insert of v into ascending 5-list.
// Closed form: t_i' = med3(t_{i-1}, t_i, v) (old values), t0' = min(t0, v).
#define INSERT5(t0, t1, t2, t3, t4, v)                \
  do {                                                \
    float _v = (v);                                   \
    float _n4 = __builtin_amdgcn_fmed3f(t3, t4, _v);  \
    float _n3 = __builtin_amdgcn_fmed3f(t2, t3, _v);  \
    float _n2 = __builtin_amdgcn_fmed3f(t1, t2, _v);  \
    float _n1 = __builtin_amdgcn_fmed3f(t0, t1, _v);  \
    t0 = fminf(t0, _v);                               \
    t1 = _n1; t2 = _n2; t3 = _n3; t4 = _n4;           \
  } while (0)

// fp4 e2m1 (OCP MXFP4) round-to-nearest encode: grid 0,.5,1,1.5,2,3,4,6.
__device__ __forceinline__ u32 f2fp4(float x) {
  u32 s = (__float_as_uint(x) >> 31) << 3;
  float a = fabsf(x);
  u32 m;
  if (a < 1.25f) m = (a < 0.25f) ? 0u : ((a < 0.75f) ? 1u : 2u);
  else if (a < 2.5f) m = (a < 1.75f) ? 3u : 4u;
  else m = (a < 3.5f) ? 5u : ((a < 5.f) ? 6u : 7u);
  return s | m;
}

// ---------------------------------------------------------------------------
// Kernel 0: fused fp4-e2m1 convert (to 32x32x64 f8f6f4 MX-fp4 band pack)
// + row sumsq (fp32 exact). MX fp4 A/B fragment (4 VGPR, 16 B): row=lane&31,
// k = (lane>>5)*32 + nibble (32 CONTIGUOUS k-nibbles per lane -- fp8 layout
// with bytes->nibbles). Band layout (64 rows, byte address within Xp4):
//   band G = row>>6 (16384 B); iter I = k>>6 (2048 B); mf2 = (row>>5)&1 (1024);
//   frag_lane = ((k>>5)&1)*32 + (row&31) (16 B); byte = (k&31)>>1; nib = k&1.
__global__ __launch_bounds__(256) void k_prep(const float* __restrict__ X,
                                              u8* __restrict__ Xp4,
                                              float* __restrict__ sq) {
  int gt = blockIdx.x * 256 + threadIdx.x;
  int row = gt >> 6;
  int lane = gt & 63;   // holds k = lane*8 .. lane*8+7 (8 elements -> 1 u32)
  const float* r = X + (size_t)row * DIM + lane * 8;
  float4 a = *(const float4*)r;
  float4 b = *(const float4*)(r + 4);
  float s = a.x * a.x + a.y * a.y + a.z * a.z + a.w * a.w
          + b.x * b.x + b.y * b.y + b.z * b.z + b.w * b.w;
  u32 w = f2fp4(a.x) | (f2fp4(a.y) << 4) | (f2fp4(a.z) << 8) |
          (f2fp4(a.w) << 12) | (f2fp4(b.x) << 16) | (f2fp4(b.y) << 20) |
          (f2fp4(b.z) << 24) | (f2fp4(b.w) << 28);
  // k0 = lane*8: I = lane>>3; k-half = (lane>>2)&1; byte = (lane&3)*4
  u32 dst = (u32)((row >> 6) * 16384 + (lane >> 3) * 2048 +
                  ((row >> 5) & 1) * 1024 +
                  (((lane >> 2) & 1) * 32 + (row & 31)) * 16 + (lane & 3) * 4);
  *(u32*)(Xp4 + dst) = w;
#pragma unroll
  for (int o = 32; o > 0; o >>= 1) s += __shfl_down(s, o);
  if (lane == 0) sq[row] = s;
}

// ---------------------------------------------------------------------------
// Kernel 1: symmetric MX-fp4 32x32x64 MFMA distance tiles, triangular grid.
// R18/R22 schedule (flatmm dbuf prefetch) but fp4 operands: 16B fragments
// (4 VMEM instr/iter, half the bytes of fp8) at the SAME MFMA count ->
// L1/L2 traffic halves, Xp4 = 2 MB (deep-L2-resident per XCD).
// cbsz/blgp = 4 (E2M1); scale e8m0 127 = 1.0.
// C/D layout shape-determined: col=lane&31, row=(reg&3)+8*(reg>>2)+4*(lane>>5)
// -> epilogues identical to R18. part holds SQUARED distances.
__global__ __launch_bounds__(256, 3) void k_knn_sym(
    const u8* __restrict__ Xp4, const float* __restrict__ sq,
    float* __restrict__ part) {
  __shared__ __align__(16) char smem[34816];
  float* mbuf = (float*)smem;             // col-epi merge: [wm*2+wn][nf2][32][5]
  float* lsT = (float*)smem;              // row-epi transpose: [128 cols][68]

  const int tid = threadIdx.x;
  const int lane = tid & 63;
  const int wid = tid >> 6;
  const int wm = wid >> 1;
  const int wn = wid & 1;
  const int lh = lane >> 5;               // row-half selector for C/D

  // XCD-aware bijective remap (2080 = 8 * 260) -> 8x8 super-tiles per XCD
  int t = (blockIdx.x & 7) * 260 + (blockIdx.x >> 3);
  int bm, bn;
  if (t < 1792) {
    int st = t >> 6, u = t & 63;
    int SM = (int)((sqrtf(8.f * st + 1.f) + 1.f) * 0.5f);
    while (SM * (SM - 1) / 2 > st) --SM;
    while ((SM + 1) * SM / 2 <= st) ++SM;
    int SN = st - SM * (SM - 1) / 2;
    bm = SM * 8 + (u >> 3);
    bn = SN * 8 + (u & 7);
  } else {
    int d = t - 1792;
    int SM = d / 36, u = d % 36;
    int im = (int)((sqrtf(8.f * u + 1.f) - 1.f) * 0.5f);
    while ((im + 1) * (im + 2) / 2 <= u) ++im;
    while (im * (im + 1) / 2 > u) --im;
    int in = u - im * (im + 1) / 2;
    bm = SM * 8 + im;
    bn = SM * 8 + in;
  }
  const int n0 = bm * 128;
  const int q0 = bn * 128;

  // Band pointers: band (64 rows) = 16384 B; advance 2048 B per K-64 iter.
  // 16B-aligned (lane*16) for i32x4 loads.
  const u8* pa = Xp4 + (size_t)(bm * 2 + wm) * 16384 + lane * 16;
  const u8* pb = Xp4 + (size_t)(bn * 2 + wn) * 16384 + lane * 16;

  i32x8 afr[2][2], bfr[2][2];             // [buf][mf2/nf2]; low 4 regs = data
#define LD16(dst, p)                                           \
  do {                                                         \
    i32x4 _t = *(const i32x4*)(p);                             \
    dst[0] = _t[0]; dst[1] = _t[1];                            \
    dst[2] = _t[2]; dst[3] = _t[3];                            \
    dst[4] = 0; dst[5] = 0; dst[6] = 0; dst[7] = 0;            \
  } while (0)
#define LOADF(buf)                                             \
  do {                                                         \
    LD16(afr[buf][0], pa);                                     \
    LD16(afr[buf][1], pa + 1024);                              \
    LD16(bfr[buf][0], pb);                                     \
    LD16(bfr[buf][1], pb + 1024);                              \
  } while (0)

  f32x16 acc[2][2];
#pragma unroll
  for (int mf2 = 0; mf2 < 2; ++mf2)
#pragma unroll
    for (int nf2 = 0; nf2 < 2; ++nf2)
#pragma unroll
      for (int r = 0; r < 16; ++r) acc[mf2][nf2][r] = 0.f;

  LOADF(0);

#pragma unroll
  for (int step = 0; step < DIM / 64; ++step) {        // 8 iters of K=64
    const int cur = step & 1;
    if (step < DIM / 64 - 1) {
      pa += 2048;
      pb += 2048;
      LOADF(cur ^ 1);                                  // prefetch next iter
    }
    __builtin_amdgcn_sched_barrier(0);
#pragma unroll
    for (int mf2 = 0; mf2 < 2; ++mf2)
#pragma unroll
      for (int nf2 = 0; nf2 < 2; ++nf2)
        acc[mf2][nf2] = __builtin_amdgcn_mfma_scale_f32_32x32x64_f8f6f4(
            afr[cur][mf2], bfr[cur][nf2], acc[mf2][nf2],
            4, 4,            // cbsz/blgp: fp4 e2m1 / fp4 e2m1
            0, 127,          // scale A: opsel 0, e8m0 127 = 1.0
            0, 127);         // scale B: opsel 0, e8m0 127 = 1.0
  }
#undef LOADF
#undef LD16

  // ---- column epilogue: per query-col top-5 of (sq_row - 2*dot) ----
  int qg[2];
  float sqc[2];
#pragma unroll
  for (int nf2 = 0; nf2 < 2; ++nf2) {
    qg[nf2] = q0 + wn * 64 + nf2 * 32 + (lane & 31);
    sqc[nf2] = sq[qg[nf2]];
  }

  float tl[2][5];
#pragma unroll
  for (int nf2 = 0; nf2 < 2; ++nf2)
#pragma unroll
    for (int j = 0; j < 5; ++j) tl[nf2][j] = 1e30f;

  // diagonal mask needed only on the 64 diagonal tiles (uniform branch)
#define COLSCAN(DIAG)                                                         \
  do {                                                                        \
    _Pragma("unroll")                                                         \
    for (int mf2 = 0; mf2 < 2; ++mf2) {                                       \
      _Pragma("unroll")                                                       \
      for (int q2 = 0; q2 < 4; ++q2) {                                        \
        int ngb = n0 + wm * 64 + mf2 * 32 + q2 * 8 + 4 * lh;                  \
        float4 snv = *(const float4*)&sq[ngb];                                \
        _Pragma("unroll")                                                     \
        for (int j = 0; j < 4; ++j) {                                         \
          float sn = (j == 0) ? snv.x : (j == 1) ? snv.y                      \
                   : (j == 2) ? snv.z : snv.w;                                \
          _Pragma("unroll")                                                   \
          for (int nf2 = 0; nf2 < 2; ++nf2) {                                 \
            float c = fmaf(-2.f, acc[mf2][nf2][q2 * 4 + j], sn);              \
            if (DIAG) c = ((ngb + j) == qg[nf2]) ? -1e30f : c;                \
            INSERT5(tl[nf2][0], tl[nf2][1], tl[nf2][2], tl[nf2][3],           \
                    tl[nf2][4], c);                                           \
          }                                                                   \
        }                                                                     \
      }                                                                       \
    }                                                                         \
  } while (0)

  if (bm == bn) COLSCAN(true); else COLSCAN(false);
#undef COLSCAN

  // merge with partner lane^32 (holds the complementary 32 rows, same col)
#pragma unroll
  for (int nf2 = 0; nf2 < 2; ++nf2) {
    float v0 = __shfl_xor(tl[nf2][0], 32);
    float v1 = __shfl_xor(tl[nf2][1], 32);
    float v2 = __shfl_xor(tl[nf2][2], 32);
    float v3 = __shfl_xor(tl[nf2][3], 32);
    float v4 = __shfl_xor(tl[nf2][4], 32);
    INSERT5(tl[nf2][0], tl[nf2][1], tl[nf2][2], tl[nf2][3], tl[nf2][4], v0);
    INSERT5(tl[nf2][0], tl[nf2][1], tl[nf2][2], tl[nf2][3], tl[nf2][4], v1);
    INSERT5(tl[nf2][0], tl[nf2][1], tl[nf2][2], tl[nf2][3], tl[nf2][4], v2);
    INSERT5(tl[nf2][0], tl[nf2][1], tl[nf2][2], tl[nf2][3], tl[nf2][4], v3);
    INSERT5(tl[nf2][0], tl[nf2][1], tl[nf2][2], tl[nf2][3], tl[nf2][4], v4);
  }

  if (lane < 32) {
#pragma unroll
    for (int nf2 = 0; nf2 < 2; ++nf2)
#pragma unroll
      for (int j = 0; j < 5; ++j)
        mbuf[(((wm * 2 + wn) * 2 + nf2) * 32 + lane) * 5 + j] = tl[nf2][j];
  }
  __syncthreads();

  if (tid < 128) {
    int wn2 = tid >> 6, nf2 = (tid >> 5) & 1, q = tid & 31;
    const float* m0 = &mbuf[(((0 * 2 + wn2) * 2 + nf2) * 32 + q) * 5];
    const float* m1 = &mbuf[(((1 * 2 + wn2) * 2 + nf2) * 32 + q) * 5];
    float b0 = m0[0], b1 = m0[1], b2 = m0[2], b3 = m0[3], b4 = m0[4];
#pragma unroll
    for (int j = 0; j < 5; ++j) {
      float v = m1[j];
      INSERT5(b0, b1, b2, b3, b4, v);
    }
    int qgl = q0 + wn2 * 64 + nf2 * 32 + q;
    float sc = sq[qgl];
    float* o = part + ((size_t)qgl * (NPTS / 128) + bm) * KNN;
    o[0] = b0 + sc;   // squared distances; sqrt deferred to k_merge
    o[1] = b1 + sc;
    o[2] = b2 + sc;
    o[3] = b3 + sc;
    o[4] = b4 + sc;
  }

  // ---- row epilogue (off-diagonal blocks): queries = this tile's rows ----
  // pass p = mf2: rows {wm*64 + p*32 + w32} through lsT[128 cols][68 rows].
  if (bm != bn) {
#pragma unroll
    for (int p = 0; p < 2; ++p) {
      __syncthreads();                     // protect mbuf / previous readers
#pragma unroll
      for (int nf2 = 0; nf2 < 2; ++nf2) {
        int cl = wn * 64 + nf2 * 32 + (lane & 31);
#pragma unroll
        for (int q2 = 0; q2 < 4; ++q2) {
          int rl = wm * 32 + q2 * 8 + 4 * lh;
          f32x4 cp;
#pragma unroll
          for (int j = 0; j < 4; ++j)
            cp[j] = fmaf(-2.f, acc[p][nf2][q2 * 4 + j], sqc[nf2]);
          *(f32x4*)&lsT[cl * 68 + rl] = cp;   // 16B-aligned (rl%4==0)
        }
      }
      __syncthreads();
      int r = tid >> 2, qq = tid & 3;        // 4 threads per row, 32 cols each
      float b0 = 1e30f, b1 = 1e30f, b2 = 1e30f, b3 = 1e30f, b4 = 1e30f;
#pragma unroll
      for (int j = 0; j < 32; ++j) {
        int i = (j + 2 * qq) & 31;           // conflict-free read order
        float v = lsT[(qq * 32 + i) * 68 + r];
        INSERT5(b0, b1, b2, b3, b4, v);
      }
#pragma unroll
      for (int m = 1; m <= 2; m <<= 1) {
        float v0 = __shfl_xor(b0, m);
        float v1 = __shfl_xor(b1, m);
        float v2 = __shfl_xor(b2, m);
        float v3 = __shfl_xor(b3, m);
        float v4 = __shfl_xor(b4, m);
        INSERT5(b0, b1, b2, b3, b4, v0);
        INSERT5(b0, b1, b2, b3, b4, v1);
        INSERT5(b0, b1, b2, b3, b4, v2);
        INSERT5(b0, b1, b2, b3, b4, v3);
        INSERT5(b0, b1, b2, b3, b4, v4);
      }
      if ((tid & 3) == 0) {
        int ng = n0 + (r >> 5) * 64 + p * 32 + (r & 31);
        float sn = sq[ng];
        float* o = part + ((size_t)ng * (NPTS / 128) + bn) * KNN;
        o[0] = b0 + sn;   // squared distances
        o[1] = b1 + sn;
        o[2] = b2 + sn;
        o[3] = b3 + sn;
        o[4] = b4 + sn;
      }
    }
  }
}

// ---------------------------------------------------------------------------
// Kernel 2: fold 64 partial top-5 (of d^2) per query -> per-block (sum, sum2)
// of DISTANCES (sqrt applied to the final 5 only).
__global__ __launch_bounds__(256) void k_merge(const float* __restrict__ part,
                                               double* __restrict__ pacc) {
  __shared__ double red[8];
  int tid = threadIdx.x;
  int q = blockIdx.x * 64 + (tid >> 2);
  int quarter = tid & 3;
  const float4* p =
      (const float4*)(part + ((size_t)q * (NPTS / 128) + quarter * 16) * KNN);
  float b0 = 1e30f, b1 = 1e30f, b2 = 1e30f, b3 = 1e30f, b4 = 1e30f;
#pragma unroll
  for (int i = 0; i < 20; ++i) {
    float4 v = p[i];
    INSERT5(b0, b1, b2, b3, b4, v.x);
    INSERT5(b0, b1, b2, b3, b4, v.y);
    INSERT5(b0, b1, b2, b3, b4, v.z);
    INSERT5(b0, b1, b2, b3, b4, v.w);
  }
#pragma unroll
  for (int m = 1; m <= 2; m <<= 1) {
    float v0 = __shfl_xor(b0, m);
    float v1 = __shfl_xor(b1, m);
    float v2 = __shfl_xor(b2, m);
    float v3 = __shfl_xor(b3, m);
    float v4 = __shfl_xor(b4, m);
    INSERT5(b0, b1, b2, b3, b4, v0);
    INSERT5(b0, b1, b2, b3, b4, v1);
    INSERT5(b0, b1, b2, b3, b4, v2);
    INSERT5(b0, b1, b2, b3, b4, v3);
    INSERT5(b0, b1, b2, b3, b4, v4);
  }
  double ds = 0.0, ds2 = 0.0;
  if ((tid & 3) == 0) {
    float d0 = sqrtf(fmaxf(b0, 0.f));
    float d1 = sqrtf(fmaxf(b1, 0.f));
    float d2 = sqrtf(fmaxf(b2, 0.f));
    float d3 = sqrtf(fmaxf(b3, 0.f));
    float d4 = sqrtf(fmaxf(b4, 0.f));
    float s = d0 + d1 + d2 + d3 + d4;
    float s2 = d0 * d0 + d1 * d1 + d2 * d2 + d3 * d3 + d4 * d4;
    ds = (double)s;
    ds2 = (double)s2;
  }
#pragma unroll
  for (int o = 32; o > 0; o >>= 1) {
    ds += __shfl_down(ds, o);
    ds2 += __shfl_down(ds2, o);
  }
  if ((tid & 63) == 0) {
    red[2 * (tid >> 6)] = ds;
    red[2 * (tid >> 6) + 1] = ds2;
  }
  __syncthreads();
  if (tid == 0) {
    double s = red[0] + red[2] + red[4] + red[6];
    double s2 = red[1] + red[3] + red[5] + red[7];
    pacc[2 * blockIdx.x] = s;
    pacc[2 * blockIdx.x + 1] = s2;
  }
}

// Kernel 3: fold 128 block partials -> -std(knn_dist, ddof=1)
__global__ void k_final(const double* __restrict__ pacc, float* __restrict__ out) {
  int lane = threadIdx.x;
  double s = pacc[2 * lane] + pacc[2 * (lane + 64)];
  double s2 = pacc[2 * lane + 1] + pacc[2 * (lane + 64) + 1];
#pragma unroll
  for (int o = 32; o > 0; o >>= 1) {
    s += __shfl_down(s, o);
    s2 += __shfl_down(s2, o);
  }
  if (lane == 0) {
    double n = (double)NPTS * (double)KNN;
    double mean = s / n;
    double var = (s2 - n * mean * mean) / (n - 1.0);
    if (var < 0.0) var = 0.0;
    out[0] = -(float)sqrt(var);
  }
}

// ---------------------------------------------------------------------------
extern "C" void kernel_launch(void* const* d_in, const int* in_sizes, int n_in,
                              void* d_out, int out_size, void* d_ws, size_t ws_size,
                              hipStream_t stream) {
  const float* X = (const float*)d_in[0];  // latent[0]
  char* ws = (char*)d_ws;

  // ws: part [8192][64][5] f32 (10.5 MB) | sq [8192] f32 | pacc [256] f64 | Xp4 fp4 packed (2 MB)
  const size_t PART_B = (size_t)NPTS * (NPTS / 128) * KNN * 4;
  float* part = (float*)ws;
  float* sq = (float*)(ws + PART_B);
  double* pacc = (double*)(ws + PART_B + 32768);
  u8* Xp4 = (u8*)(ws + PART_B + 32768 + 2048);
  float* out = (float*)d_out;

  const int NT = NPTS / 128;                       // 64 tiles per dim
  hipLaunchKernelGGL(k_prep, dim3(NPTS / 4), dim3(256), 0, stream, X, Xp4, sq);
  hipLaunchKernelGGL(k_knn_sym, dim3(NT * (NT + 1) / 2), dim3(256), 0, stream,
                     Xp4, sq, part);
  hipLaunchKernelGGL(k_merge, dim3(NPTS / 64), dim3(256), 0, stream, part, pacc);
  hipLaunchKernelGGL(k_final, dim3(1), dim3(64), 0, stream, pacc, out);
}